// Round 10
// baseline (154.864 us; speedup 1.0000x reference)
//
#include <hip/hip_runtime.h>
#include <stdint.h>

#define B 16
#define CIN 32
#define C 64
#define H 256
#define W 256
#define OH 86
#define OW 86
#define PIX (OH*OW)   // 7396
#define PADW 272
#define PWORDS (PADW*PADW*8)   // 591,872 words per n-slice

typedef int v4i __attribute__((ext_vector_type(4)));

// ---- workspace layout (bytes) ----
#define OFF_D      0          // 3 u32: bit patterns of max|w11|, max|w1|, max|w2|
#define OFF_MAPW   64         // 24 i32: [g8][s3] packed mapped words (s = v+1)
#define OFF_B11    768        // 64 i32
#define OFF_B2     1280       // 64 i32
#define OFF_TLO    1536       // 64 i32: conv1 integer threshold lo (bias folded)
#define OFF_THI    1792       // 64 i32: conv1 integer threshold hi
#define OFF_W11R   4096       // 4608 i32: [pos9][q1 2][cot4][c16][j4]
#define OFF_W1R    24576      // 4608 i32: [pos9][q1 2][cot4][c16][j4]
#define OFF_W2R    45056      // 9216 i32: [pos9][cot4][c16][q4][j4]
#define OFF_XTP    262144     // padded [n16][272][272][32B] raw tern(x)  = 37.9MB
#define OFF_XMAP   38141952   // padded [n16][272][272][32B] mapped       = 37.9MB

__device__ __forceinline__ int tern_i(float t, float d) {
    return (fabsf(t) < d) ? 0 : (t > 0.f ? 1 : -1);
}

// ---------------- K0a: zero absmax slots + padded-tensor borders ----------------
__global__ __launch_bounds__(256) void k_pad(char* ws) {
    int idx = blockIdx.x * 256 + threadIdx.x;
    if (blockIdx.x == 0 && threadIdx.x < 3)
        ((unsigned*)(ws + OFF_D))[threadIdx.x] = 0u;
    if (idx >= 135168) return;                 // 16n x 8448 border cells
    int n = idx / 8448, c = idx - n * 8448;
    int row, col;
    if (c < 4352) {                            // rows {0,1,258..271} full width
        int r = c / 272; col = c - r * 272; row = (r < 2) ? r : r + 256;
    } else {                                   // rows 2..257, cols {0,1,258..271}
        int c2 = c - 4352; int k = c2 & 15;
        row = 2 + (c2 >> 4); col = (k < 2) ? k : k + 256;
    }
    size_t base = ((size_t)n * (PADW * PADW) + (size_t)row * PADW + col) * 2;  // int4 units
    int4 z = make_int4(0, 0, 0, 0);
    ((int4*)(ws + OFF_XTP))[base] = z;  ((int4*)(ws + OFF_XTP))[base + 1] = z;
    ((int4*)(ws + OFF_XMAP))[base] = z; ((int4*)(ws + OFF_XMAP))[base + 1] = z;
}

// ---------------- K0b: max|w| via bitwise atomicMax ----------------
__global__ __launch_bounds__(256) void k_absmax(const float* w11, const float* w1,
                                                const float* w2, unsigned* dws) {
    __shared__ unsigned red[256];
    int b = blockIdx.x >> 4, sub = blockIdx.x & 15;
    const float* p = (b == 0) ? w11 : (b == 1) ? w1 : w2;
    int n = (b == 2) ? 36864 : 18432;
    int chunk = (n + 15) >> 4;
    int lo = sub * chunk, hi = min(lo + chunk, n);
    unsigned m = 0;
    for (int i = lo + threadIdx.x; i < hi; i += 256)
        m = max(m, __float_as_uint(fabsf(p[i])));
    red[threadIdx.x] = m; __syncthreads();
    for (int s = 128; s > 0; s >>= 1) {
        if (threadIdx.x < s) red[threadIdx.x] = max(red[threadIdx.x], red[threadIdx.x + s]);
        __syncthreads();
    }
    if (threadIdx.x == 0) atomicMax(&dws[b], red[0]);
}

// ---------------- K1: pack weights, tables, integer thresholds ----------------
__global__ __launch_bounds__(256) void k_prep(const float* w11, const float* w1, const float* w2,
                                              const float* b11, const float* b1, const float* b2,
                                              const float* gp, const float* bp, const float* mp, const float* vp,
                                              const float* g1, const float* be1, const float* me1, const float* v1,
                                              char* ws) {
    const unsigned* dw = (const unsigned*)(ws + OFF_D);
    float d11 = __fmul_rn(0.1f, __uint_as_float(dw[0]));
    float d1  = __fmul_rn(0.1f, __uint_as_float(dw[1]));
    float d2v = __fmul_rn(0.1f, __uint_as_float(dw[2]));
    int idx = blockIdx.x * 256 + threadIdx.x;
    if (idx < 4608) {                       // w1r [pos][q1][cot4][c16][j]
        int j = idx & 3, c16 = (idx >> 2) & 15, cot = (idx >> 6) & 3;
        int q1 = (idx >> 8) & 1, pos = idx >> 9;
        int co = cot * 16 + c16;
        unsigned wd = 0;
        #pragma unroll
        for (int jj = 0; jj < 4; jj++) {
            int ci = q1 * 16 + j * 4 + jj;
            int tv = tern_i(w1[(co * 32 + ci) * 9 + pos], d1);
            wd |= ((unsigned)(tv & 255)) << (8 * jj);
        }
        ((int*)(ws + OFF_W1R))[idx] = (int)wd;
    } else if (idx < 9216) {                // w11r [pos][q1][cot4][c16][j]
        int i2 = idx - 4608;
        int j = i2 & 3, c16 = (i2 >> 2) & 15, cot = (i2 >> 6) & 3;
        int q1 = (i2 >> 8) & 1, pos = i2 >> 9;
        int co = cot * 16 + c16;
        unsigned wd = 0;
        #pragma unroll
        for (int jj = 0; jj < 4; jj++) {
            int ci = q1 * 16 + j * 4 + jj;
            int tv = tern_i(w11[(co * 32 + ci) * 9 + pos], d11);
            wd |= ((unsigned)(tv & 255)) << (8 * jj);
        }
        ((int*)(ws + OFF_W11R))[i2] = (int)wd;
    } else if (idx < 18432) {               // w2r [pos][cot4][c16][q4][j4]
        int i2 = idx - 9216;
        int j = i2 & 3, q = (i2 >> 2) & 3, c16 = (i2 >> 4) & 15;
        int cot = (i2 >> 8) & 3, pos = i2 >> 10;
        int co = cot * 16 + c16;
        unsigned wd = 0;
        #pragma unroll
        for (int jj = 0; jj < 4; jj++) {
            int ci = q * 16 + j * 4 + jj;
            int tv = tern_i(w2[(co * 64 + ci) * 9 + pos], d2v);
            wd |= ((unsigned)(tv & 255)) << (8 * jj);
        }
        ((int*)(ws + OFF_W2R))[i2] = (int)wd;
    } else {
        int i = idx - 18432;
        if (i < 64) {
            ((int*)(ws + OFF_B11))[i] = tern_i(b11[i], d11);
        } else if (i < 128) {
            ((int*)(ws + OFF_B2))[i - 64] = tern_i(b2[i - 64], d2v);
        } else if (i < 152) {
            int j = i - 128;                // 0..23 : mapw[g*3 + (v+1)]
            int g = j / 3, s = j % 3;
            float v = (float)(s - 1);
            unsigned wd = 0;
            #pragma unroll
            for (int jj = 0; jj < 4; jj++) {
                int c = g * 4 + jj;
                float inv = __fdiv_rn(gp[c], __fsqrt_rn(__fadd_rn(vp[c], 1e-5f)));
                float sh  = __fsub_rn(bp[c], __fmul_rn(mp[c], inv));
                float z   = __fadd_rn(__fmul_rn(v, inv), sh);
                z = (z > 0.f) ? z : __fmul_rn(0.01f, z);
                wd |= ((unsigned)(tern_i(z, d1) & 255)) << (8 * jj);
            }
            ((int*)(ws + OFF_MAPW))[j] = (int)wd;
        } else if (i < 216) {
            // integer thresholds for conv1 epilogue: class(vi) is monotone
            // nondecreasing in vi since inv = g1/sqrt(var+eps) >= 0.
            int co = i - 152;
            float inv = __fdiv_rn(g1[co], __fsqrt_rn(__fadd_rn(v1[co], 1e-5f)));
            float sh  = __fsub_rn(be1[co], __fmul_rn(me1[co], inv));
            int lo = 1000, hi = 1000;
            for (int vi = -290; vi <= 290; ++vi) {
                float z = __fadd_rn(__fmul_rn((float)vi, inv), sh);
                z = (z > 0.f) ? z : __fmul_rn(0.01f, z);
                int cls = (fabsf(z) < d2v) ? 0 : (z > 0.f ? 1 : -1);
                if (cls >= 0 && lo == 1000) lo = vi;
                if (cls == 1 && hi == 1000) hi = vi;
            }
            int b1t = tern_i(b1[co], d1);   // fold conv1 ternary bias
            ((int*)(ws + OFF_TLO))[co] = lo - b1t;
            ((int*)(ws + OFF_THI))[co] = hi - b1t;
        }
    }
}

// ---------------- K2: x -> padded raw tern + padded mapped ----------------
__global__ __launch_bounds__(256) void k_tern_x(const float* __restrict__ x,
                                                char* __restrict__ ws) {
    float d11 = __fmul_rn(0.1f, __uint_as_float(((const unsigned*)(ws + OFF_D))[0]));
    const int* mapw = (const int*)(ws + OFF_MAPW);
    int idx = blockIdx.x * 256 + threadIdx.x;      // 1,048,576 threads
    int pix = idx & 65535, n = idx >> 16;
    int y = pix >> 8, xq = pix & 255;
    const float* xp = x + ((size_t)n * CIN << 16) + pix;
    int rw[8], mw[8];
    #pragma unroll
    for (int g = 0; g < 8; ++g) {
        unsigned r = 0, m = 0;
        #pragma unroll
        for (int j = 0; j < 4; ++j) {
            float v = xp[(size_t)(g * 4 + j) << 16];
            int tv = tern_i(v, d11);
            r |= ((unsigned)(tv & 255)) << (8 * j);
            m |= (((unsigned)mapw[g * 3 + tv + 1] >> (8 * j)) & 255u) << (8 * j);
        }
        rw[g] = (int)r; mw[g] = (int)m;
    }
    size_t base = ((size_t)n * (PADW * PADW) + (size_t)(y + 2) * PADW + (xq + 2)) * 2;
    int4* o1 = (int4*)(ws + OFF_XTP) + base;
    o1[0] = make_int4(rw[0], rw[1], rw[2], rw[3]);
    o1[1] = make_int4(rw[4], rw[5], rw[6], rw[7]);
    int4* o2 = (int4*)(ws + OFF_XMAP) + base;
    o2[0] = make_int4(mw[0], mw[1], mw[2], mw[3]);
    o2[1] = make_int4(mw[4], mw[5], mw[6], mw[7]);
}

// ---------------- K3: fused conv1+conv2+conv11, one barrier ----------------
// grid 11x11x16. 4 waves; lane = (q,c16); q1 = ci-half, qh = pos parity.
// t2L: [576 px][16 words], word-group XOR-swizzled by ((p>>1)&3) -> 36.9KB, 4 blocks/CU.
__global__ __launch_bounds__(256, 4) void k_net(const char* __restrict__ ws,
                                                float* __restrict__ out) {
    __shared__ int t2L[576 * 16];   // 36864 B
    int tid = threadIdx.x, bid = blockIdx.x;
    int tx = bid % 11; int tt = bid / 11; int ty = tt % 11; int n = tt / 11;
    int OH0 = ty * 8, OW0 = tx * 8;
    int Y0 = OH0 * 3 - 2, X0 = OW0 * 3 - 2;      // 26x26 halo origin (global)
    int c16 = tid & 15, q = (tid >> 4) & 3, wv = tid >> 6;
    int q1 = q & 1, qh = q >> 1;
    const int* xmapn = (const int*)(ws + OFF_XMAP) + (size_t)n * PWORDS;
    const int* xtpn  = (const int*)(ws + OFF_XTP)  + (size_t)n * PWORDS;

    // ---- conv1: B-frags for all 64 co hoisted (80 VGPR) ----
    const int* w1r = (const int*)(ws + OFF_W1R);
    v4i bw1[5][4];
    #pragma unroll
    for (int c = 0; c < 5; ++c) {
        int pos = 2 * c + qh;
        #pragma unroll
        for (int ct = 0; ct < 4; ++ct) {
            v4i z = {0, 0, 0, 0};
            if (pos < 9) z = *(const v4i*)&w1r[((pos * 2 + q1) * 4 + ct) * 64 + c16 * 4];
            bw1[c][ct] = z;
        }
    }
    const int* TLO = (const int*)(ws + OFF_TLO);
    const int* THI = (const int*)(ws + OFF_THI);
    int tlo[4], thi[4];
    #pragma unroll
    for (int ct = 0; ct < 4; ++ct) { tlo[ct] = TLO[ct * 16 + c16]; thi[ct] = THI[ct * 16 + c16]; }

    int Yb = Y0 + 2, Xb = X0 + 2;                // padded coords
    #pragma unroll 1
    for (int pg = 0; pg < 9; ++pg) {
        int pbase = (wv * 9 + pg) * 16;
        int fp = pbase + c16;                    // A-row pixel (0..575)
        int iy = fp / 24, ix = fp - iy * 24;
        v4i a[5];
        #pragma unroll
        for (int c = 0; c < 5; ++c) {
            int pos = 2 * c + qh;
            v4i z = {0, 0, 0, 0};
            if (pos < 9) {
                int kh = pos / 3, kw = pos - kh * 3;
                z = *(const v4i*)&xmapn[((Yb + iy + kh) * PADW + (Xb + ix + kw)) * 8 + q1 * 4];
            }
            a[c] = z;
        }
        int pwr = pbase + q * 4 + (c16 & 3);     // write pixel after transpose
        int wy = pwr / 24, wx = pwr - wy * 24;
        bool wok = ((unsigned)(Y0 + 1 + wy) < H) && ((unsigned)(X0 + 1 + wx) < W);
        int wsw = (pwr >> 1) & 3;                // XOR swizzle key for this pixel
        #pragma unroll
        for (int ct = 0; ct < 4; ++ct) {
            v4i acc = {0, 0, 0, 0};
            #pragma unroll
            for (int c = 0; c < 5; ++c)
                acc = __builtin_amdgcn_mfma_i32_16x16x64_i8(a[c], bw1[c][ct], acc, 0, 0, 0);
            // integer-threshold epilogue: class = (vi>=lo)+(vi>=hi)-1
            unsigned wcol = 0;
            #pragma unroll
            for (int i = 0; i < 4; ++i) {
                int cls = (acc[i] >= tlo[ct] ? 1 : 0) + (acc[i] >= thi[ct] ? 1 : 0) - 1;
                wcol |= ((unsigned)(cls & 255)) << (8 * i);
            }
            // 4x4 byte transpose across lanes (c16&3): co-major -> pixel-major
            unsigned y1 = (unsigned)__shfl_xor((int)wcol, 1);
            unsigned z1 = ((c16 & 1) == 0)
                        ? __builtin_amdgcn_perm(y1, wcol, 0x06020400u)
                        : __builtin_amdgcn_perm(y1, wcol, 0x03070105u);
            unsigned y2 = (unsigned)__shfl_xor((int)z1, 2);
            unsigned r  = ((c16 & 2) == 0)
                        ? __builtin_amdgcn_perm(y2, z1, 0x05040100u)
                        : __builtin_amdgcn_perm(y2, z1, 0x03020706u);
            t2L[pwr * 16 + (ct ^ wsw) * 4 + (c16 >> 2)] = wok ? (int)r : 0;
        }
    }
    __syncthreads();

    // ---- conv11 A-loads (padded, unconditional) ----
    int o = wv * 16 + c16;
    int oh8 = o >> 3, ow8 = o & 7;
    int gOH = OH0 + oh8, gOW = OW0 + ow8;
    v4i a11[5];
    #pragma unroll
    for (int c = 0; c < 5; ++c) {
        int pos = 2 * c + qh;
        v4i z = {0, 0, 0, 0};
        if (pos < 9) {
            int kh = pos / 3, kw = pos - kh * 3;
            int ih = gOH * 3 - 1 + kh, iw = gOW * 3 - 1 + kw;
            z = *(const v4i*)&xtpn[((ih + 2) * PADW + (iw + 2)) * 8 + q1 * 4];
        }
        a11[c] = z;
    }
    // ---- conv2 A from LDS (K = all 64 ci per chunk), swizzled groups ----
    v4i a2[9];
    #pragma unroll
    for (int pos = 0; pos < 9; ++pos) {
        int kh = pos / 3, kw = pos - kh * 3;
        int p2 = (oh8 * 3 + kh) * 24 + ow8 * 3 + kw;
        int g2 = q ^ ((p2 >> 1) & 3);
        a2[pos] = *(const v4i*)&t2L[p2 * 16 + g2 * 4];
    }
    const int* w2r = (const int*)(ws + OFF_W2R);
    const int* w11r = (const int*)(ws + OFF_W11R);
    v4i acc2[4], acc11[4];
    #pragma unroll
    for (int ct = 0; ct < 4; ++ct) {
        v4i acc = {0, 0, 0, 0};
        #pragma unroll
        for (int pos = 0; pos < 9; ++pos) {
            v4i b = *(const v4i*)&w2r[((pos * 4 + ct) * 16 + c16) * 16 + q * 4];
            acc = __builtin_amdgcn_mfma_i32_16x16x64_i8(a2[pos], b, acc, 0, 0, 0);
        }
        acc2[ct] = acc;
        v4i acc1 = {0, 0, 0, 0};
        #pragma unroll
        for (int c = 0; c < 5; ++c) {
            int pos = 2 * c + qh;
            v4i b = {0, 0, 0, 0};
            if (pos < 9) b = *(const v4i*)&w11r[((pos * 2 + q1) * 4 + ct) * 64 + c16 * 4];
            acc1 = __builtin_amdgcn_mfma_i32_16x16x64_i8(a11[c], b, acc1, 0, 0, 0);
        }
        acc11[ct] = acc1;
    }

    // ---- final epilogue: + b2 + b11, lrelu -> out ----
    const int* b2i = (const int*)(ws + OFF_B2);
    const int* b11i = (const int*)(ws + OFF_B11);
    int pt0 = wv * 16 + q * 4;
    int ohh = OH0 + (pt0 >> 3);
    int oww = OW0 + (pt0 & 7);
    if (ohh < OH) {
        #pragma unroll
        for (int ct = 0; ct < 4; ++ct) {
            int co = ct * 16 + c16;
            int bc = b2i[co] + b11i[co];
            float f[4];
            #pragma unroll
            for (int i = 0; i < 4; ++i) {
                float z = (float)(acc2[ct][i] + acc11[ct][i] + bc);
                f[i] = (z > 0.f) ? z : __fmul_rn(0.01f, z);
            }
            float* op = out + ((size_t)(n * 64 + co)) * PIX + ohh * OW + oww;
            if (oww + 3 < OW) {
                *(float4*)op = make_float4(f[0], f[1], f[2], f[3]);
            } else {
                #pragma unroll
                for (int i = 0; i < 4; ++i)
                    if (oww + i < OW) op[i] = f[i];
            }
        }
    }
}

extern "C" void kernel_launch(void* const* d_in, const int* in_sizes, int n_in,
                              void* d_out, int out_size, void* d_ws, size_t ws_size,
                              hipStream_t stream) {
    const float* x    = (const float*)d_in[0];
    const float* w11  = (const float*)d_in[1];
    const float* b11  = (const float*)d_in[2];
    const float* w1   = (const float*)d_in[3];
    const float* b1   = (const float*)d_in[4];
    const float* w2   = (const float*)d_in[5];
    const float* b2   = (const float*)d_in[6];
    const float* gp   = (const float*)d_in[7];
    const float* bp   = (const float*)d_in[8];
    const float* mp   = (const float*)d_in[9];
    const float* vp   = (const float*)d_in[10];
    const float* g1   = (const float*)d_in[11];
    const float* be1  = (const float*)d_in[12];
    const float* me1  = (const float*)d_in[13];
    const float* v1   = (const float*)d_in[14];
    char* ws = (char*)d_ws;
    float* out = (float*)d_out;

    k_pad<<<528, 256, 0, stream>>>(ws);
    k_absmax<<<48, 256, 0, stream>>>(w11, w1, w2, (unsigned*)(ws + OFF_D));
    k_prep<<<73, 256, 0, stream>>>(w11, w1, w2, b11, b1, b2,
                                   gp, bp, mp, vp, g1, be1, me1, v1, ws);
    k_tern_x<<<4096, 256, 0, stream>>>(x, ws);
    k_net<<<11 * 11 * B, 256, 0, stream>>>(ws, out);
}

// Round 11
// 143.767 us; speedup vs baseline: 1.0772x; 1.0772x over previous
//
#include <hip/hip_runtime.h>
#include <stdint.h>

#define B 16
#define CIN 32
#define C 64
#define H 256
#define W 256
#define OH 86
#define OW 86
#define PIX (OH*OW)   // 7396
#define PADW 272
#define PWORDS (PADW*PADW*8)   // 591,872 words per n-slice

typedef int v4i __attribute__((ext_vector_type(4)));

// ---- workspace layout (bytes) ----
#define OFF_D      0          // 3 u32: bit patterns of max|w11|, max|w1|, max|w2|
#define OFF_MAPW   64         // 24 i32: [g8][s3] packed mapped words (s = v+1)
#define OFF_B11    768        // 64 i32
#define OFF_B2     1280       // 64 i32
#define OFF_TLO    1536       // 64 i32: conv1 integer threshold lo (bias folded)
#define OFF_THI    1792       // 64 i32: conv1 integer threshold hi
#define OFF_W11R   4096       // 4608 i32: [pos9][q1 2][cot4][c16][j4]
#define OFF_W1R    24576      // 4608 i32: [pos9][q1 2][cot4][c16][j4]
#define OFF_W2R    45056      // 9216 i32: [pos9][cot4][c16][q4][j4]
#define OFF_XTP    262144     // padded [n16][272][272][32B] raw tern(x)  = 37.9MB
#define OFF_XMAP   38141952   // padded [n16][272][272][32B] mapped       = 37.9MB

__device__ __forceinline__ int tern_i(float t, float d) {
    return (fabsf(t) < d) ? 0 : (t > 0.f ? 1 : -1);
}

// ---------------- K0a: zero absmax slots + padded-tensor borders ----------------
__global__ __launch_bounds__(256) void k_pad(char* ws) {
    int idx = blockIdx.x * 256 + threadIdx.x;
    if (blockIdx.x == 0 && threadIdx.x < 3)
        ((unsigned*)(ws + OFF_D))[threadIdx.x] = 0u;
    if (idx >= 135168) return;                 // 16n x 8448 border cells
    int n = idx / 8448, c = idx - n * 8448;
    int row, col;
    if (c < 4352) {                            // rows {0,1,258..271} full width
        int r = c / 272; col = c - r * 272; row = (r < 2) ? r : r + 256;
    } else {                                   // rows 2..257, cols {0,1,258..271}
        int c2 = c - 4352; int k = c2 & 15;
        row = 2 + (c2 >> 4); col = (k < 2) ? k : k + 256;
    }
    size_t base = ((size_t)n * (PADW * PADW) + (size_t)row * PADW + col) * 2;  // int4 units
    int4 z = make_int4(0, 0, 0, 0);
    ((int4*)(ws + OFF_XTP))[base] = z;  ((int4*)(ws + OFF_XTP))[base + 1] = z;
    ((int4*)(ws + OFF_XMAP))[base] = z; ((int4*)(ws + OFF_XMAP))[base + 1] = z;
}

// ---------------- K0b: max|w| via bitwise atomicMax ----------------
__global__ __launch_bounds__(256) void k_absmax(const float* w11, const float* w1,
                                                const float* w2, unsigned* dws) {
    __shared__ unsigned red[256];
    int b = blockIdx.x >> 4, sub = blockIdx.x & 15;
    const float* p = (b == 0) ? w11 : (b == 1) ? w1 : w2;
    int n = (b == 2) ? 36864 : 18432;
    int chunk = (n + 15) >> 4;
    int lo = sub * chunk, hi = min(lo + chunk, n);
    unsigned m = 0;
    for (int i = lo + threadIdx.x; i < hi; i += 256)
        m = max(m, __float_as_uint(fabsf(p[i])));
    red[threadIdx.x] = m; __syncthreads();
    for (int s = 128; s > 0; s >>= 1) {
        if (threadIdx.x < s) red[threadIdx.x] = max(red[threadIdx.x], red[threadIdx.x + s]);
        __syncthreads();
    }
    if (threadIdx.x == 0) atomicMax(&dws[b], red[0]);
}

// ---------------- K1: pack weights, tables, integer thresholds ----------------
__global__ __launch_bounds__(256) void k_prep(const float* w11, const float* w1, const float* w2,
                                              const float* b11, const float* b1, const float* b2,
                                              const float* gp, const float* bp, const float* mp, const float* vp,
                                              const float* g1, const float* be1, const float* me1, const float* v1,
                                              char* ws) {
    const unsigned* dw = (const unsigned*)(ws + OFF_D);
    float d11 = __fmul_rn(0.1f, __uint_as_float(dw[0]));
    float d1  = __fmul_rn(0.1f, __uint_as_float(dw[1]));
    float d2v = __fmul_rn(0.1f, __uint_as_float(dw[2]));
    int idx = blockIdx.x * 256 + threadIdx.x;
    if (idx < 4608) {                       // w1r [pos][q1][cot4][c16][j]
        int j = idx & 3, c16 = (idx >> 2) & 15, cot = (idx >> 6) & 3;
        int q1 = (idx >> 8) & 1, pos = idx >> 9;
        int co = cot * 16 + c16;
        unsigned wd = 0;
        #pragma unroll
        for (int jj = 0; jj < 4; jj++) {
            int ci = q1 * 16 + j * 4 + jj;
            int tv = tern_i(w1[(co * 32 + ci) * 9 + pos], d1);
            wd |= ((unsigned)(tv & 255)) << (8 * jj);
        }
        ((int*)(ws + OFF_W1R))[idx] = (int)wd;
    } else if (idx < 9216) {                // w11r [pos][q1][cot4][c16][j]
        int i2 = idx - 4608;
        int j = i2 & 3, c16 = (i2 >> 2) & 15, cot = (i2 >> 6) & 3;
        int q1 = (i2 >> 8) & 1, pos = i2 >> 9;
        int co = cot * 16 + c16;
        unsigned wd = 0;
        #pragma unroll
        for (int jj = 0; jj < 4; jj++) {
            int ci = q1 * 16 + j * 4 + jj;
            int tv = tern_i(w11[(co * 32 + ci) * 9 + pos], d11);
            wd |= ((unsigned)(tv & 255)) << (8 * jj);
        }
        ((int*)(ws + OFF_W11R))[i2] = (int)wd;
    } else if (idx < 18432) {               // w2r [pos][cot4][c16][q4][j4]
        int i2 = idx - 9216;
        int j = i2 & 3, q = (i2 >> 2) & 3, c16 = (i2 >> 4) & 15;
        int cot = (i2 >> 8) & 3, pos = i2 >> 10;
        int co = cot * 16 + c16;
        unsigned wd = 0;
        #pragma unroll
        for (int jj = 0; jj < 4; jj++) {
            int ci = q * 16 + j * 4 + jj;
            int tv = tern_i(w2[(co * 64 + ci) * 9 + pos], d2v);
            wd |= ((unsigned)(tv & 255)) << (8 * jj);
        }
        ((int*)(ws + OFF_W2R))[i2] = (int)wd;
    } else {
        int i = idx - 18432;
        if (i < 64) {
            ((int*)(ws + OFF_B11))[i] = tern_i(b11[i], d11);
        } else if (i < 128) {
            ((int*)(ws + OFF_B2))[i - 64] = tern_i(b2[i - 64], d2v);
        } else if (i < 152) {
            int j = i - 128;                // 0..23 : mapw[g*3 + (v+1)]
            int g = j / 3, s = j % 3;
            float v = (float)(s - 1);
            unsigned wd = 0;
            #pragma unroll
            for (int jj = 0; jj < 4; jj++) {
                int c = g * 4 + jj;
                float inv = __fdiv_rn(gp[c], __fsqrt_rn(__fadd_rn(vp[c], 1e-5f)));
                float sh  = __fsub_rn(bp[c], __fmul_rn(mp[c], inv));
                float z   = __fadd_rn(__fmul_rn(v, inv), sh);
                z = (z > 0.f) ? z : __fmul_rn(0.01f, z);
                wd |= ((unsigned)(tern_i(z, d1) & 255)) << (8 * jj);
            }
            ((int*)(ws + OFF_MAPW))[j] = (int)wd;
        } else if (i < 216) {
            // integer thresholds for conv1 epilogue: class(vi) is monotone
            // nondecreasing in vi since inv = g1/sqrt(var+eps) >= 0.
            int co = i - 152;
            float inv = __fdiv_rn(g1[co], __fsqrt_rn(__fadd_rn(v1[co], 1e-5f)));
            float sh  = __fsub_rn(be1[co], __fmul_rn(me1[co], inv));
            int lo = 1000, hi = 1000;
            for (int vi = -290; vi <= 290; ++vi) {
                float z = __fadd_rn(__fmul_rn((float)vi, inv), sh);
                z = (z > 0.f) ? z : __fmul_rn(0.01f, z);
                int cls = (fabsf(z) < d2v) ? 0 : (z > 0.f ? 1 : -1);
                if (cls >= 0 && lo == 1000) lo = vi;
                if (cls == 1 && hi == 1000) hi = vi;
            }
            int b1t = tern_i(b1[co], d1);   // fold conv1 ternary bias
            ((int*)(ws + OFF_TLO))[co] = lo - b1t;
            ((int*)(ws + OFF_THI))[co] = hi - b1t;
        }
    }
}

// ---------------- K2: x -> padded raw tern + padded mapped ----------------
__global__ __launch_bounds__(256) void k_tern_x(const float* __restrict__ x,
                                                char* __restrict__ ws) {
    float d11 = __fmul_rn(0.1f, __uint_as_float(((const unsigned*)(ws + OFF_D))[0]));
    const int* mapw = (const int*)(ws + OFF_MAPW);
    int idx = blockIdx.x * 256 + threadIdx.x;      // 1,048,576 threads
    int pix = idx & 65535, n = idx >> 16;
    int y = pix >> 8, xq = pix & 255;
    const float* xp = x + ((size_t)n * CIN << 16) + pix;
    int rw[8], mw[8];
    #pragma unroll
    for (int g = 0; g < 8; ++g) {
        unsigned r = 0, m = 0;
        #pragma unroll
        for (int j = 0; j < 4; ++j) {
            float v = xp[(size_t)(g * 4 + j) << 16];
            int tv = tern_i(v, d11);
            r |= ((unsigned)(tv & 255)) << (8 * j);
            m |= (((unsigned)mapw[g * 3 + tv + 1] >> (8 * j)) & 255u) << (8 * j);
        }
        rw[g] = (int)r; mw[g] = (int)m;
    }
    size_t base = ((size_t)n * (PADW * PADW) + (size_t)(y + 2) * PADW + (xq + 2)) * 2;
    int4* o1 = (int4*)(ws + OFF_XTP) + base;
    o1[0] = make_int4(rw[0], rw[1], rw[2], rw[3]);
    o1[1] = make_int4(rw[4], rw[5], rw[6], rw[7]);
    int4* o2 = (int4*)(ws + OFF_XMAP) + base;
    o2[0] = make_int4(mw[0], mw[1], mw[2], mw[3]);
    o2[1] = make_int4(mw[4], mw[5], mw[6], mw[7]);
}

// ---------------- K3: fused conv1+conv2+conv11, one barrier, pipelined ----------------
// grid 11x11x16. 4 waves; lane = (q,c16); q1 = ci-half, qh = pos parity.
// t2L: [576 px][16 words], word-group XOR-swizzled by ((p>>1)&3) -> 36.9KB.
__global__ __launch_bounds__(256, 3) void k_net(const char* __restrict__ ws,
                                                float* __restrict__ out) {
    __shared__ int t2L[576 * 16];   // 36864 B
    int tid = threadIdx.x, bid = blockIdx.x;
    int tx = bid % 11; int tt = bid / 11; int ty = tt % 11; int n = tt / 11;
    int OH0 = ty * 8, OW0 = tx * 8;
    int Y0 = OH0 * 3 - 2, X0 = OW0 * 3 - 2;      // 26x26 halo origin (global)
    int c16 = tid & 15, q = (tid >> 4) & 3, wv = tid >> 6;
    int q1 = q & 1, qh = q >> 1;
    const int* xmapn = (const int*)(ws + OFF_XMAP) + (size_t)n * PWORDS;
    const int* xtpn  = (const int*)(ws + OFF_XTP)  + (size_t)n * PWORDS;

    // ---- conv1: B-frags for all 64 co hoisted (80 VGPR) ----
    const int* w1r = (const int*)(ws + OFF_W1R);
    v4i bw1[5][4];
    #pragma unroll
    for (int c = 0; c < 5; ++c) {
        int pos = 2 * c + qh;
        #pragma unroll
        for (int ct = 0; ct < 4; ++ct) {
            v4i z = {0, 0, 0, 0};
            if (pos < 9) z = *(const v4i*)&w1r[((pos * 2 + q1) * 4 + ct) * 64 + c16 * 4];
            bw1[c][ct] = z;
        }
    }
    const int* TLO = (const int*)(ws + OFF_TLO);
    const int* THI = (const int*)(ws + OFF_THI);
    int tlo[4], thi[4];
    #pragma unroll
    for (int ct = 0; ct < 4; ++ct) { tlo[ct] = TLO[ct * 16 + c16]; thi[ct] = THI[ct * 16 + c16]; }

    int Yb = Y0 + 2, Xb = X0 + 2;                // padded coords
    // ---- prologue: A-frags for pg=0 ----
    v4i aC[5];
    {
        int fp = wv * 144 + c16;
        int iy = fp / 24, ix = fp - iy * 24;
        #pragma unroll
        for (int c = 0; c < 5; ++c) {
            int pos = 2 * c + qh;
            v4i z = {0, 0, 0, 0};
            if (pos < 9) {
                int kh = pos / 3, kw = pos - kh * 3;
                z = *(const v4i*)&xmapn[((Yb + iy + kh) * PADW + (Xb + ix + kw)) * 8 + q1 * 4];
            }
            aC[c] = z;
        }
    }
    #pragma unroll 1
    for (int pg = 0; pg < 9; ++pg) {
        // prefetch pg+1's A-frags (pg=8 reloads itself; uniform, harmless)
        int pgn = (pg < 8) ? pg + 1 : 8;
        int fpn = (wv * 9 + pgn) * 16 + c16;
        int iyn = fpn / 24, ixn = fpn - iyn * 24;
        v4i aN[5];
        #pragma unroll
        for (int c = 0; c < 5; ++c) {
            int pos = 2 * c + qh;
            v4i z = {0, 0, 0, 0};
            if (pos < 9) {
                int kh = pos / 3, kw = pos - kh * 3;
                z = *(const v4i*)&xmapn[((Yb + iyn + kh) * PADW + (Xb + ixn + kw)) * 8 + q1 * 4];
            }
            aN[c] = z;
        }
        // compute pg with aC (prefetch in flight)
        int pbase = (wv * 9 + pg) * 16;
        int pwr = pbase + q * 4 + (c16 & 3);     // write pixel after transpose
        int wy = pwr / 24, wx = pwr - wy * 24;
        bool wok = ((unsigned)(Y0 + 1 + wy) < H) && ((unsigned)(X0 + 1 + wx) < W);
        int wsw = (pwr >> 1) & 3;                // XOR swizzle key for this pixel
        #pragma unroll
        for (int ct = 0; ct < 4; ++ct) {
            v4i acc = {0, 0, 0, 0};
            #pragma unroll
            for (int c = 0; c < 5; ++c)
                acc = __builtin_amdgcn_mfma_i32_16x16x64_i8(aC[c], bw1[c][ct], acc, 0, 0, 0);
            // integer-threshold epilogue: class = (vi>=lo)+(vi>=hi)-1
            unsigned wcol = 0;
            #pragma unroll
            for (int i = 0; i < 4; ++i) {
                int cls = (acc[i] >= tlo[ct] ? 1 : 0) + (acc[i] >= thi[ct] ? 1 : 0) - 1;
                wcol |= ((unsigned)(cls & 255)) << (8 * i);
            }
            // 4x4 byte transpose across lanes (c16&3): co-major -> pixel-major
            unsigned y1 = (unsigned)__shfl_xor((int)wcol, 1);
            unsigned z1 = ((c16 & 1) == 0)
                        ? __builtin_amdgcn_perm(y1, wcol, 0x06020400u)
                        : __builtin_amdgcn_perm(y1, wcol, 0x03070105u);
            unsigned y2 = (unsigned)__shfl_xor((int)z1, 2);
            unsigned r  = ((c16 & 2) == 0)
                        ? __builtin_amdgcn_perm(y2, z1, 0x05040100u)
                        : __builtin_amdgcn_perm(y2, z1, 0x03020706u);
            t2L[pwr * 16 + (ct ^ wsw) * 4 + (c16 >> 2)] = wok ? (int)r : 0;
        }
        #pragma unroll
        for (int c = 0; c < 5; ++c) aC[c] = aN[c];
    }

    // ---- conv11 (independent of t2L): fills the barrier-drain window ----
    int o = wv * 16 + c16;
    int oh8 = o >> 3, ow8 = o & 7;
    int gOH = OH0 + oh8, gOW = OW0 + ow8;
    v4i a11[5];
    #pragma unroll
    for (int c = 0; c < 5; ++c) {
        int pos = 2 * c + qh;
        v4i z = {0, 0, 0, 0};
        if (pos < 9) {
            int kh = pos / 3, kw = pos - kh * 3;
            int ih = gOH * 3 - 1 + kh, iw = gOW * 3 - 1 + kw;
            z = *(const v4i*)&xtpn[((ih + 2) * PADW + (iw + 2)) * 8 + q1 * 4];
        }
        a11[c] = z;
    }
    const int* w11r = (const int*)(ws + OFF_W11R);
    v4i acc11[4];
    #pragma unroll
    for (int ct = 0; ct < 4; ++ct) {
        v4i acc1 = {0, 0, 0, 0};
        #pragma unroll
        for (int c = 0; c < 5; ++c) {
            int pos = 2 * c + qh;
            v4i b = {0, 0, 0, 0};
            if (pos < 9) b = *(const v4i*)&w11r[((pos * 2 + q1) * 4 + ct) * 64 + c16 * 4];
            acc1 = __builtin_amdgcn_mfma_i32_16x16x64_i8(a11[c], b, acc1, 0, 0, 0);
        }
        acc11[ct] = acc1;
    }
    __syncthreads();

    // ---- conv2 A from LDS (K = all 64 ci per chunk), swizzled groups ----
    v4i a2[9];
    #pragma unroll
    for (int pos = 0; pos < 9; ++pos) {
        int kh = pos / 3, kw = pos - kh * 3;
        int p2 = (oh8 * 3 + kh) * 24 + ow8 * 3 + kw;
        int g2 = q ^ ((p2 >> 1) & 3);
        a2[pos] = *(const v4i*)&t2L[p2 * 16 + g2 * 4];
    }
    const int* w2r = (const int*)(ws + OFF_W2R);
    v4i acc2[4];
    #pragma unroll
    for (int ct = 0; ct < 4; ++ct) {
        v4i acc = {0, 0, 0, 0};
        #pragma unroll
        for (int pos = 0; pos < 9; ++pos) {
            v4i b = *(const v4i*)&w2r[((pos * 4 + ct) * 16 + c16) * 16 + q * 4];
            acc = __builtin_amdgcn_mfma_i32_16x16x64_i8(a2[pos], b, acc, 0, 0, 0);
        }
        acc2[ct] = acc;
    }

    // ---- final epilogue: + b2 + b11, lrelu -> out ----
    const int* b2i = (const int*)(ws + OFF_B2);
    const int* b11i = (const int*)(ws + OFF_B11);
    int pt0 = wv * 16 + q * 4;
    int ohh = OH0 + (pt0 >> 3);
    int oww = OW0 + (pt0 & 7);
    if (ohh < OH) {
        #pragma unroll
        for (int ct = 0; ct < 4; ++ct) {
            int co = ct * 16 + c16;
            int bc = b2i[co] + b11i[co];
            float f[4];
            #pragma unroll
            for (int i = 0; i < 4; ++i) {
                float z = (float)(acc2[ct][i] + acc11[ct][i] + bc);
                f[i] = (z > 0.f) ? z : __fmul_rn(0.01f, z);
            }
            float* op = out + ((size_t)(n * 64 + co)) * PIX + ohh * OW + oww;
            if (oww + 3 < OW) {
                *(float4*)op = make_float4(f[0], f[1], f[2], f[3]);
            } else {
                #pragma unroll
                for (int i = 0; i < 4; ++i)
                    if (oww + i < OW) op[i] = f[i];
            }
        }
    }
}

extern "C" void kernel_launch(void* const* d_in, const int* in_sizes, int n_in,
                              void* d_out, int out_size, void* d_ws, size_t ws_size,
                              hipStream_t stream) {
    const float* x    = (const float*)d_in[0];
    const float* w11  = (const float*)d_in[1];
    const float* b11  = (const float*)d_in[2];
    const float* w1   = (const float*)d_in[3];
    const float* b1   = (const float*)d_in[4];
    const float* w2   = (const float*)d_in[5];
    const float* b2   = (const float*)d_in[6];
    const float* gp   = (const float*)d_in[7];
    const float* bp   = (const float*)d_in[8];
    const float* mp   = (const float*)d_in[9];
    const float* vp   = (const float*)d_in[10];
    const float* g1   = (const float*)d_in[11];
    const float* be1  = (const float*)d_in[12];
    const float* me1  = (const float*)d_in[13];
    const float* v1   = (const float*)d_in[14];
    char* ws = (char*)d_ws;
    float* out = (float*)d_out;

    k_pad<<<528, 256, 0, stream>>>(ws);
    k_absmax<<<48, 256, 0, stream>>>(w11, w1, w2, (unsigned*)(ws + OFF_D));
    k_prep<<<73, 256, 0, stream>>>(w11, w1, w2, b11, b1, b2,
                                   gp, bp, mp, vp, g1, be1, me1, v1, ws);
    k_tern_x<<<4096, 256, 0, stream>>>(x, ws);
    k_net<<<11 * 11 * B, 256, 0, stream>>>(ws, out);
}

// Round 12
// 139.968 us; speedup vs baseline: 1.1064x; 1.0271x over previous
//
#include <hip/hip_runtime.h>
#include <stdint.h>

#define B 16
#define CIN 32
#define C 64
#define H 256
#define W 256
#define OH 86
#define OW 86
#define PIX (OH*OW)   // 7396
#define PADW 272
#define PWORDS (PADW*PADW*8)   // 591,872 words per n-slice

typedef int v4i __attribute__((ext_vector_type(4)));

// ---- workspace layout (bytes) ----
#define OFF_D      0          // 3 u32: bit patterns of max|w11|, max|w1|, max|w2|
#define OFF_MAPW   64         // 24 i32: [g8][s3] packed mapped words (s = v+1)
#define OFF_B11    768        // 64 i32
#define OFF_B2     1280       // 64 i32
#define OFF_TLO    1536       // 64 i32: conv1 integer threshold lo (bias folded)
#define OFF_THI    1792       // 64 i32: conv1 integer threshold hi
#define OFF_W11R   4096       // 4608 i32: [pos9][q1 2][cot4][c16][j4]
#define OFF_W1R    24576      // 4608 i32: [pos9][q1 2][cot4][c16][j4]
#define OFF_W2R    45056      // 9216 i32: [pos9][cot4][c16][q4][j4]
#define OFF_XTP    262144     // padded [n16][272][272][32B] raw tern(x)  = 37.9MB
#define OFF_XMAP   38141952   // padded [n16][272][272][32B] mapped       = 37.9MB

__device__ __forceinline__ int tern_i(float t, float d) {
    return (fabsf(t) < d) ? 0 : (t > 0.f ? 1 : -1);
}

// ---------------- K0a: zero the absmax slots ----------------
__global__ void k_zero(unsigned* d) {
    if (threadIdx.x < 3) d[threadIdx.x] = 0u;
}

// ---------------- K0b: max|w| via bitwise atomicMax ----------------
__global__ __launch_bounds__(256) void k_absmax(const float* w11, const float* w1,
                                                const float* w2, unsigned* dws) {
    __shared__ unsigned red[256];
    int b = blockIdx.x >> 4, sub = blockIdx.x & 15;
    const float* p = (b == 0) ? w11 : (b == 1) ? w1 : w2;
    int n = (b == 2) ? 36864 : 18432;
    int chunk = (n + 15) >> 4;
    int lo = sub * chunk, hi = min(lo + chunk, n);
    unsigned m = 0;
    for (int i = lo + threadIdx.x; i < hi; i += 256)
        m = max(m, __float_as_uint(fabsf(p[i])));
    red[threadIdx.x] = m; __syncthreads();
    for (int s = 128; s > 0; s >>= 1) {
        if (threadIdx.x < s) red[threadIdx.x] = max(red[threadIdx.x], red[threadIdx.x + s]);
        __syncthreads();
    }
    if (threadIdx.x == 0) atomicMax(&dws[b], red[0]);
}

// ---------------- K1: pack weights, tables, integer thresholds ----------------
__global__ __launch_bounds__(256) void k_prep(const float* w11, const float* w1, const float* w2,
                                              const float* b11, const float* b1, const float* b2,
                                              const float* gp, const float* bp, const float* mp, const float* vp,
                                              const float* g1, const float* be1, const float* me1, const float* v1,
                                              char* ws) {
    const unsigned* dw = (const unsigned*)(ws + OFF_D);
    float d11 = __fmul_rn(0.1f, __uint_as_float(dw[0]));
    float d1  = __fmul_rn(0.1f, __uint_as_float(dw[1]));
    float d2v = __fmul_rn(0.1f, __uint_as_float(dw[2]));
    int idx = blockIdx.x * 256 + threadIdx.x;
    if (idx < 4608) {                       // w1r [pos][q1][cot4][c16][j]
        int j = idx & 3, c16 = (idx >> 2) & 15, cot = (idx >> 6) & 3;
        int q1 = (idx >> 8) & 1, pos = idx >> 9;
        int co = cot * 16 + c16;
        unsigned wd = 0;
        #pragma unroll
        for (int jj = 0; jj < 4; jj++) {
            int ci = q1 * 16 + j * 4 + jj;
            int tv = tern_i(w1[(co * 32 + ci) * 9 + pos], d1);
            wd |= ((unsigned)(tv & 255)) << (8 * jj);
        }
        ((int*)(ws + OFF_W1R))[idx] = (int)wd;
    } else if (idx < 9216) {                // w11r [pos][q1][cot4][c16][j]
        int i2 = idx - 4608;
        int j = i2 & 3, c16 = (i2 >> 2) & 15, cot = (i2 >> 6) & 3;
        int q1 = (i2 >> 8) & 1, pos = i2 >> 9;
        int co = cot * 16 + c16;
        unsigned wd = 0;
        #pragma unroll
        for (int jj = 0; jj < 4; jj++) {
            int ci = q1 * 16 + j * 4 + jj;
            int tv = tern_i(w11[(co * 32 + ci) * 9 + pos], d11);
            wd |= ((unsigned)(tv & 255)) << (8 * jj);
        }
        ((int*)(ws + OFF_W11R))[i2] = (int)wd;
    } else if (idx < 18432) {               // w2r [pos][cot4][c16][q4][j4]
        int i2 = idx - 9216;
        int j = i2 & 3, q = (i2 >> 2) & 3, c16 = (i2 >> 4) & 15;
        int cot = (i2 >> 8) & 3, pos = i2 >> 10;
        int co = cot * 16 + c16;
        unsigned wd = 0;
        #pragma unroll
        for (int jj = 0; jj < 4; jj++) {
            int ci = q * 16 + j * 4 + jj;
            int tv = tern_i(w2[(co * 64 + ci) * 9 + pos], d2v);
            wd |= ((unsigned)(tv & 255)) << (8 * jj);
        }
        ((int*)(ws + OFF_W2R))[i2] = (int)wd;
    } else {
        int i = idx - 18432;
        if (i < 64) {
            ((int*)(ws + OFF_B11))[i] = tern_i(b11[i], d11);
        } else if (i < 128) {
            ((int*)(ws + OFF_B2))[i - 64] = tern_i(b2[i - 64], d2v);
        } else if (i < 152) {
            int j = i - 128;                // 0..23 : mapw[g*3 + (v+1)]
            int g = j / 3, s = j % 3;
            float v = (float)(s - 1);
            unsigned wd = 0;
            #pragma unroll
            for (int jj = 0; jj < 4; jj++) {
                int c = g * 4 + jj;
                float inv = __fdiv_rn(gp[c], __fsqrt_rn(__fadd_rn(vp[c], 1e-5f)));
                float sh  = __fsub_rn(bp[c], __fmul_rn(mp[c], inv));
                float z   = __fadd_rn(__fmul_rn(v, inv), sh);
                z = (z > 0.f) ? z : __fmul_rn(0.01f, z);
                wd |= ((unsigned)(tern_i(z, d1) & 255)) << (8 * jj);
            }
            ((int*)(ws + OFF_MAPW))[j] = (int)wd;
        } else if (i < 216) {
            // integer thresholds for conv1 epilogue: class(vi) is monotone
            // nondecreasing in vi since inv = g1/sqrt(var+eps) >= 0.
            int co = i - 152;
            float inv = __fdiv_rn(g1[co], __fsqrt_rn(__fadd_rn(v1[co], 1e-5f)));
            float sh  = __fsub_rn(be1[co], __fmul_rn(me1[co], inv));
            int lo = 1000, hi = 1000;
            for (int vi = -290; vi <= 290; ++vi) {
                float z = __fadd_rn(__fmul_rn((float)vi, inv), sh);
                z = (z > 0.f) ? z : __fmul_rn(0.01f, z);
                int cls = (fabsf(z) < d2v) ? 0 : (z > 0.f ? 1 : -1);
                if (cls >= 0 && lo == 1000) lo = vi;
                if (cls == 1 && hi == 1000) hi = vi;
            }
            int b1t = tern_i(b1[co], d1);   // fold conv1 ternary bias
            ((int*)(ws + OFF_TLO))[co] = lo - b1t;
            ((int*)(ws + OFF_THI))[co] = hi - b1t;
        }
    }
}

// ---------------- K2: x -> padded raw tern + padded mapped (+ border zeroing) ----------------
__global__ __launch_bounds__(256) void k_tern_x(const float* __restrict__ x,
                                                char* __restrict__ ws) {
    int bidx = blockIdx.x;
    if (bidx >= 4096) {
        // border zeroing (formerly k_pad): 16n x 8448 cells
        int idx = (bidx - 4096) * 256 + threadIdx.x;
        int n = idx / 8448, c = idx - n * 8448;
        int row, col;
        if (c < 4352) {                            // rows {0,1,258..271} full width
            int r = c / 272; col = c - r * 272; row = (r < 2) ? r : r + 256;
        } else {                                   // rows 2..257, cols {0,1,258..271}
            int c2 = c - 4352; int k = c2 & 15;
            row = 2 + (c2 >> 4); col = (k < 2) ? k : k + 256;
        }
        size_t base = ((size_t)n * (PADW * PADW) + (size_t)row * PADW + col) * 2;
        int4 z = make_int4(0, 0, 0, 0);
        ((int4*)(ws + OFF_XTP))[base] = z;  ((int4*)(ws + OFF_XTP))[base + 1] = z;
        ((int4*)(ws + OFF_XMAP))[base] = z; ((int4*)(ws + OFF_XMAP))[base + 1] = z;
        return;
    }
    float d11 = __fmul_rn(0.1f, __uint_as_float(((const unsigned*)(ws + OFF_D))[0]));
    const int* mapw = (const int*)(ws + OFF_MAPW);
    int idx = bidx * 256 + threadIdx.x;            // 1,048,576 threads
    int pix = idx & 65535, n = idx >> 16;
    int y = pix >> 8, xq = pix & 255;
    const float* xp = x + ((size_t)n * CIN << 16) + pix;
    int rw[8], mw[8];
    #pragma unroll
    for (int g = 0; g < 8; ++g) {
        unsigned r = 0, m = 0;
        #pragma unroll
        for (int j = 0; j < 4; ++j) {
            float v = xp[(size_t)(g * 4 + j) << 16];
            int tv = tern_i(v, d11);
            r |= ((unsigned)(tv & 255)) << (8 * j);
            m |= (((unsigned)mapw[g * 3 + tv + 1] >> (8 * j)) & 255u) << (8 * j);
        }
        rw[g] = (int)r; mw[g] = (int)m;
    }
    size_t base = ((size_t)n * (PADW * PADW) + (size_t)(y + 2) * PADW + (xq + 2)) * 2;
    int4* o1 = (int4*)(ws + OFF_XTP) + base;
    o1[0] = make_int4(rw[0], rw[1], rw[2], rw[3]);
    o1[1] = make_int4(rw[4], rw[5], rw[6], rw[7]);
    int4* o2 = (int4*)(ws + OFF_XMAP) + base;
    o2[0] = make_int4(mw[0], mw[1], mw[2], mw[3]);
    o2[1] = make_int4(mw[4], mw[5], mw[6], mw[7]);
}

// ---------------- K3: fused conv1+conv2+conv11, one barrier, swapped conv1 ----------------
// grid 11x11x16. 4 waves; lane = (q,c16); q1 = ci-half, qh = pos parity.
// conv1 computes D = W1 x X  -> lane (q,c16) holds 4 consecutive co for ONE pixel (c16)
// => t2 word written directly, no cross-lane transpose.
// t2L: [576 px][16 words], word-group XOR-swizzled by ((px>>1)&3) -> 36.9KB.
__global__ __launch_bounds__(256, 3) void k_net(const char* __restrict__ ws,
                                                float* __restrict__ out) {
    __shared__ int t2L[576 * 16];   // 36864 B
    int tid = threadIdx.x, bid = blockIdx.x;
    int tx = bid % 11; int tt = bid / 11; int ty = tt % 11; int n = tt / 11;
    int OH0 = ty * 8, OW0 = tx * 8;
    int Y0 = OH0 * 3 - 2, X0 = OW0 * 3 - 2;      // 26x26 halo origin (global)
    int c16 = tid & 15, q = (tid >> 4) & 3, wv = tid >> 6;
    int q1 = q & 1, qh = q >> 1;
    const int* xmapn = (const int*)(ws + OFF_XMAP) + (size_t)n * PWORDS;
    const int* xtpn  = (const int*)(ws + OFF_XTP)  + (size_t)n * PWORDS;

    // ---- conv1: A-operand (weights) for all 64 co hoisted (80 VGPR) ----
    const int* w1r = (const int*)(ws + OFF_W1R);
    v4i bw1[5][4];
    #pragma unroll
    for (int c = 0; c < 5; ++c) {
        int pos = 2 * c + qh;
        #pragma unroll
        for (int ct = 0; ct < 4; ++ct) {
            v4i z = {0, 0, 0, 0};
            if (pos < 9) z = *(const v4i*)&w1r[((pos * 2 + q1) * 4 + ct) * 64 + c16 * 4];
            bw1[c][ct] = z;
        }
    }
    // thresholds for this lane's co = ct*16 + q*4 + i
    const int* TLO = (const int*)(ws + OFF_TLO);
    const int* THI = (const int*)(ws + OFF_THI);
    v4i tlo4[4], thi4[4];
    #pragma unroll
    for (int ct = 0; ct < 4; ++ct) {
        tlo4[ct] = *(const v4i*)&TLO[ct * 16 + q * 4];
        thi4[ct] = *(const v4i*)&THI[ct * 16 + q * 4];
    }

    int Yb = Y0 + 2, Xb = X0 + 2;                // padded coords
    #pragma unroll 1
    for (int pg = 0; pg < 9; ++pg) {
        int pbase = (wv * 9 + pg) * 16;
        int fp = pbase + c16;                    // this lane's B-column pixel (0..575)
        int iy = fp / 24, ix = fp - iy * 24;
        v4i a[5];
        #pragma unroll
        for (int c = 0; c < 5; ++c) {
            int pos = 2 * c + qh;
            v4i z = {0, 0, 0, 0};
            if (pos < 9) {
                int kh = pos / 3, kw = pos - kh * 3;
                z = *(const v4i*)&xmapn[((Yb + iy + kh) * PADW + (Xb + ix + kw)) * 8 + q1 * 4];
            }
            a[c] = z;
        }
        // validity of this pixel for t2 (conv2 zero-padding)
        bool wok = ((unsigned)(Y0 + 1 + iy) < H) && ((unsigned)(X0 + 1 + ix) < W);
        int key = (fp >> 1) & 3;                 // XOR swizzle key
        #pragma unroll
        for (int ct = 0; ct < 4; ++ct) {
            v4i acc = {0, 0, 0, 0};
            #pragma unroll
            for (int c = 0; c < 5; ++c)
                acc = __builtin_amdgcn_mfma_i32_16x16x64_i8(bw1[c][ct], a[c], acc, 0, 0, 0);
            // lane holds co = ct*16 + q*4 + i for pixel fp -> pack one ci-word directly
            unsigned wcol = 0;
            #pragma unroll
            for (int i = 0; i < 4; ++i) {
                int cls = (acc[i] >= tlo4[ct][i] ? 1 : 0) + (acc[i] >= thi4[ct][i] ? 1 : 0) - 1;
                wcol |= ((unsigned)(cls & 255)) << (8 * i);
            }
            // logical word w = ct*4 + q of pixel fp; stored group = (w>>2)^key, within = w&3
            t2L[fp * 16 + ((ct ^ key) << 2) + q] = wok ? (int)wcol : 0;
        }
    }

    // ---- conv11 (independent of t2L): fills the barrier-drain window ----
    int o = wv * 16 + c16;
    int oh8 = o >> 3, ow8 = o & 7;
    int gOH = OH0 + oh8, gOW = OW0 + ow8;
    v4i a11[5];
    #pragma unroll
    for (int c = 0; c < 5; ++c) {
        int pos = 2 * c + qh;
        v4i z = {0, 0, 0, 0};
        if (pos < 9) {
            int kh = pos / 3, kw = pos - kh * 3;
            int ih = gOH * 3 - 1 + kh, iw = gOW * 3 - 1 + kw;
            z = *(const v4i*)&xtpn[((ih + 2) * PADW + (iw + 2)) * 8 + q1 * 4];
        }
        a11[c] = z;
    }
    const int* w11r = (const int*)(ws + OFF_W11R);
    v4i acc11[4];
    #pragma unroll
    for (int ct = 0; ct < 4; ++ct) {
        v4i acc1 = {0, 0, 0, 0};
        #pragma unroll
        for (int c = 0; c < 5; ++c) {
            int pos = 2 * c + qh;
            v4i b = {0, 0, 0, 0};
            if (pos < 9) b = *(const v4i*)&w11r[((pos * 2 + q1) * 4 + ct) * 64 + c16 * 4];
            acc1 = __builtin_amdgcn_mfma_i32_16x16x64_i8(a11[c], b, acc1, 0, 0, 0);
        }
        acc11[ct] = acc1;
    }
    __syncthreads();

    // ---- conv2 A from LDS (K = all 64 ci per chunk), swizzled groups ----
    v4i a2[9];
    #pragma unroll
    for (int pos = 0; pos < 9; ++pos) {
        int kh = pos / 3, kw = pos - kh * 3;
        int p2 = (oh8 * 3 + kh) * 24 + ow8 * 3 + kw;
        int g2 = q ^ ((p2 >> 1) & 3);
        a2[pos] = *(const v4i*)&t2L[p2 * 16 + g2 * 4];
    }
    const int* w2r = (const int*)(ws + OFF_W2R);
    v4i acc2[4];
    #pragma unroll
    for (int ct = 0; ct < 4; ++ct) {
        v4i acc = {0, 0, 0, 0};
        #pragma unroll
        for (int pos = 0; pos < 9; ++pos) {
            v4i b = *(const v4i*)&w2r[((pos * 4 + ct) * 16 + c16) * 16 + q * 4];
            acc = __builtin_amdgcn_mfma_i32_16x16x64_i8(a2[pos], b, acc, 0, 0, 0);
        }
        acc2[ct] = acc;
    }

    // ---- final epilogue: + b2 + b11, lrelu -> out ----
    const int* b2i = (const int*)(ws + OFF_B2);
    const int* b11i = (const int*)(ws + OFF_B11);
    int pt0 = wv * 16 + q * 4;
    int ohh = OH0 + (pt0 >> 3);
    int oww = OW0 + (pt0 & 7);
    if (ohh < OH) {
        #pragma unroll
        for (int ct = 0; ct < 4; ++ct) {
            int co = ct * 16 + c16;
            int bc = b2i[co] + b11i[co];
            float f[4];
            #pragma unroll
            for (int i = 0; i < 4; ++i) {
                float z = (float)(acc2[ct][i] + acc11[ct][i] + bc);
                f[i] = (z > 0.f) ? z : __fmul_rn(0.01f, z);
            }
            float* op = out + ((size_t)(n * 64 + co)) * PIX + ohh * OW + oww;
            if (oww + 3 < OW) {
                *(float4*)op = make_float4(f[0], f[1], f[2], f[3]);
            } else {
                #pragma unroll
                for (int i = 0; i < 4; ++i)
                    if (oww + i < OW) op[i] = f[i];
            }
        }
    }
}

extern "C" void kernel_launch(void* const* d_in, const int* in_sizes, int n_in,
                              void* d_out, int out_size, void* d_ws, size_t ws_size,
                              hipStream_t stream) {
    const float* x    = (const float*)d_in[0];
    const float* w11  = (const float*)d_in[1];
    const float* b11  = (const float*)d_in[2];
    const float* w1   = (const float*)d_in[3];
    const float* b1   = (const float*)d_in[4];
    const float* w2   = (const float*)d_in[5];
    const float* b2   = (const float*)d_in[6];
    const float* gp   = (const float*)d_in[7];
    const float* bp   = (const float*)d_in[8];
    const float* mp   = (const float*)d_in[9];
    const float* vp   = (const float*)d_in[10];
    const float* g1   = (const float*)d_in[11];
    const float* be1  = (const float*)d_in[12];
    const float* me1  = (const float*)d_in[13];
    const float* v1   = (const float*)d_in[14];
    char* ws = (char*)d_ws;
    float* out = (float*)d_out;

    k_zero<<<1, 64, 0, stream>>>((unsigned*)(ws + OFF_D));
    k_absmax<<<48, 256, 0, stream>>>(w11, w1, w2, (unsigned*)(ws + OFF_D));
    k_prep<<<73, 256, 0, stream>>>(w11, w1, w2, b11, b1, b2,
                                   gp, bp, mp, vp, g1, be1, me1, v1, ws);
    k_tern_x<<<4096 + 528, 256, 0, stream>>>(x, ws);
    k_net<<<11 * 11 * B, 256, 0, stream>>>(ws, out);
}